// Round 2
// baseline (310.454 us; speedup 1.0000x reference)
//
#include <hip/hip_runtime.h>

constexpr int DEG   = 31;   // neighbors per node
constexpr int NEV   = 32;   // events per node (self + neighbors)
constexpr int TH    = 16;   // threshold: track dp[0..15] + absorbing "over"
constexpr int BLK   = 128;  // 15872 B LDS -> 10 blocks/CU if VGPR<=102

__global__ void zero_out_kernel(float* out) {
    if (threadIdx.x == 0) out[0] = 0.0f;
}

__device__ __forceinline__ float fast_sigmoid(float x) {
    return 1.0f / (1.0f + __expf(-x));
}

__global__ __launch_bounds__(BLK)
void pgl_kernel(const float* __restrict__ gains,
                const int*   __restrict__ nbr,
                float*       __restrict__ out,
                int n) {
    __shared__ int s_idx[BLK * DEG];          // 15872 B
    __shared__ float s_red[BLK / 64];

    const int tid        = threadIdx.x;
    const int blockStart = blockIdx.x * BLK;

    // ---- stage this block's neighbor rows into LDS, coalesced ----
    // base byte offset = blockIdx*128*31*4 -> multiple of 16: int4 loads OK.
    const int rows  = min(BLK, n - blockStart);
    const int elems = rows * DEG;
    const int base  = blockStart * DEG;

    const int4* nb4 = (const int4*)(nbr + base);
    int4*       s4  = (int4*)s_idx;
    const int nvec  = elems >> 2;
    for (int v = tid; v < nvec; v += BLK) s4[v] = nb4[v];
    for (int e = (nvec << 2) + tid; e < elems; e += BLK) s_idx[e] = nbr[base + e];
    __syncthreads();

    float local = 0.0f;
    const int i = blockStart + tid;
    if (i < n) {
        const int* row = s_idx + tid * DEG;  // stride-31 LDS: conflict-free

        // ---- phase 1: pull all 31 indices out of LDS into registers ----
        int idxv[DEG];
        #pragma unroll
        for (int j = 0; j < DEG; ++j) idxv[j] = row[j];

        // ---- phase 2: issue ALL gathers before any dependent math (MLP) ----
        float pv[NEV];
        pv[0] = gains[i];
        #pragma unroll
        for (int j = 0; j < DEG; ++j) pv[j + 1] = gains[idxv[j]];

        // ---- phase 3: sigmoids ----
        #pragma unroll
        for (int j = 0; j < NEV; ++j) pv[j] = fast_sigmoid(pv[j]);

        // ---- phase 4: absorbing-state Poisson-binomial DP ----
        float dp[TH];
        dp[0] = 1.0f;
        #pragma unroll
        for (int k = 1; k < TH; ++k) dp[k] = 0.0f;
        float over = 0.0f;

        #pragma unroll
        for (int j = 0; j < NEV; ++j) {
            const float pj = pv[j];
            if (j >= TH - 1) over = fmaf(dp[TH - 1], pj, over);
            const int kmax = (j + 1 < TH - 1) ? (j + 1) : (TH - 1);
            #pragma unroll
            for (int k = kmax; k >= 1; --k)
                dp[k] = fmaf(pj, dp[k - 1] - dp[k], dp[k]);
            dp[0] = fmaf(-pj, dp[0], dp[0]);
        }
        // contribution to -(loss): 0.25*p0 - P(count>=16)
        local = fmaf(0.25f, pv[0], -over);
    }

    // ---- block reduction: wave shuffle -> LDS -> one atomic per block ----
    #pragma unroll
    for (int off = 32; off > 0; off >>= 1)
        local += __shfl_down(local, off, 64);
    if ((tid & 63) == 0) s_red[tid >> 6] = local;
    __syncthreads();
    if (tid == 0) {
        float s = 0.0f;
        #pragma unroll
        for (int w = 0; w < BLK / 64; ++w) s += s_red[w];
        atomicAdd(out, s);
    }
}

extern "C" void kernel_launch(void* const* d_in, const int* in_sizes, int n_in,
                              void* d_out, int out_size, void* d_ws, size_t ws_size,
                              hipStream_t stream) {
    const float* gains = (const float*)d_in[0];
    const int*   nbr   = (const int*)d_in[1];
    float*       out   = (float*)d_out;
    const int n = in_sizes[0];

    zero_out_kernel<<<1, 64, 0, stream>>>(out);
    const int grid = (n + BLK - 1) / BLK;
    pgl_kernel<<<grid, BLK, 0, stream>>>(gains, nbr, out, n);
}

// Round 3
// 305.695 us; speedup vs baseline: 1.0156x; 1.0156x over previous
//
#include <hip/hip_runtime.h>

constexpr int DEG   = 31;   // neighbors per node
constexpr int NEV   = 32;   // events per node (self + neighbors)
constexpr int TH    = 16;   // threshold: track dp[0..15] + absorbing "over"
constexpr int BLK   = 128;  // 15872 B LDS -> 10 blocks/CU; VGPR target <=102 for 20 waves/CU

__global__ void zero_out_kernel(float* out) {
    if (threadIdx.x == 0) out[0] = 0.0f;
}

__device__ __forceinline__ float fast_sigmoid(float x) {
    return 1.0f / (1.0f + __expf(-x));
}

__global__ __launch_bounds__(BLK)
void pgl_kernel(const float* __restrict__ gains,
                const int*   __restrict__ nbr,
                float*       __restrict__ out,
                int n) {
    __shared__ int s_idx[BLK * DEG];          // 15872 B
    __shared__ float s_red[BLK / 64];

    const int tid        = threadIdx.x;
    const int blockStart = blockIdx.x * BLK;

    // ---- stage this block's neighbor rows into LDS, coalesced int4 ----
    const int rows  = min(BLK, n - blockStart);
    const int elems = rows * DEG;
    const int base  = blockStart * DEG;

    const int4* nb4 = (const int4*)(nbr + base);
    int4*       s4  = (int4*)s_idx;
    const int nvec  = elems >> 2;
    for (int v = tid; v < nvec; v += BLK) s4[v] = nb4[v];
    for (int e = (nvec << 2) + tid; e < elems; e += BLK) s_idx[e] = nbr[base + e];
    __syncthreads();

    float local = 0.0f;
    const int i = blockStart + tid;
    if (i < n) {
        const int* row = s_idx + tid * DEG;  // stride-31 LDS: 2-way alias only (free)

        // ---- byte offsets for all 32 gathers (self first) ----
        unsigned off[NEV];
        off[0] = (unsigned)i << 2;
        #pragma unroll
        for (int j = 1; j < NEV; ++j) off[j] = ((unsigned)row[j - 1]) << 2;

        // ---- asm-forced gather batch: all 32 loads issued before any wait ----
        // SGPR base + 32-bit voffset form: 1 VGPR per address, 1 per result.
        float g[NEV];
        #pragma unroll
        for (int j = 0; j < NEV; ++j)
            asm volatile("global_load_dword %0, %1, %2"
                         : "=v"(g[j])
                         : "v"(off[j]), "s"(gains));

        float dp[TH];
        dp[0] = 1.0f;
        #pragma unroll
        for (int k = 1; k < TH; ++k) dp[k] = 0.0f;
        float over = 0.0f;

        // ---- wait for oldest 16 loads; tie g[0..15] so uses can't move up ----
        asm volatile("s_waitcnt vmcnt(16)"
                     : "+v"(g[0]), "+v"(g[1]), "+v"(g[2]),  "+v"(g[3]),
                       "+v"(g[4]), "+v"(g[5]), "+v"(g[6]),  "+v"(g[7]),
                       "+v"(g[8]), "+v"(g[9]), "+v"(g[10]), "+v"(g[11]),
                       "+v"(g[12]), "+v"(g[13]), "+v"(g[14]), "+v"(g[15]));

        float p0 = fast_sigmoid(g[0]);
        #pragma unroll
        for (int j = 0; j < 16; ++j) {
            const float pj = (j == 0) ? p0 : fast_sigmoid(g[j]);
            if (j >= TH - 1) over = fmaf(dp[TH - 1], pj, over);
            const int kmax = (j + 1 < TH - 1) ? (j + 1) : (TH - 1);
            #pragma unroll
            for (int k = kmax; k >= 1; --k)
                dp[k] = fmaf(pj, dp[k - 1] - dp[k], dp[k]);
            dp[0] = fmaf(-pj, dp[0], dp[0]);
        }

        // ---- drain the rest; tie g[16..31] ----
        asm volatile("s_waitcnt vmcnt(0)"
                     : "+v"(g[16]), "+v"(g[17]), "+v"(g[18]), "+v"(g[19]),
                       "+v"(g[20]), "+v"(g[21]), "+v"(g[22]), "+v"(g[23]),
                       "+v"(g[24]), "+v"(g[25]), "+v"(g[26]), "+v"(g[27]),
                       "+v"(g[28]), "+v"(g[29]), "+v"(g[30]), "+v"(g[31]));

        #pragma unroll
        for (int j = 16; j < NEV; ++j) {
            const float pj = fast_sigmoid(g[j]);
            over = fmaf(dp[TH - 1], pj, over);
            #pragma unroll
            for (int k = TH - 1; k >= 1; --k)
                dp[k] = fmaf(pj, dp[k - 1] - dp[k], dp[k]);
            dp[0] = fmaf(-pj, dp[0], dp[0]);
        }

        // contribution to -(loss): 0.25*p0 - P(count>=16)
        local = fmaf(0.25f, p0, -over);
    }

    // ---- block reduction: wave shuffle -> LDS -> one atomic per block ----
    #pragma unroll
    for (int off2 = 32; off2 > 0; off2 >>= 1)
        local += __shfl_down(local, off2, 64);
    if ((tid & 63) == 0) s_red[tid >> 6] = local;
    __syncthreads();
    if (tid == 0) {
        float s = 0.0f;
        #pragma unroll
        for (int w = 0; w < BLK / 64; ++w) s += s_red[w];
        atomicAdd(out, s);
    }
}

extern "C" void kernel_launch(void* const* d_in, const int* in_sizes, int n_in,
                              void* d_out, int out_size, void* d_ws, size_t ws_size,
                              hipStream_t stream) {
    const float* gains = (const float*)d_in[0];
    const int*   nbr   = (const int*)d_in[1];
    float*       out   = (float*)d_out;
    const int n = in_sizes[0];

    zero_out_kernel<<<1, 64, 0, stream>>>(out);
    const int grid = (n + BLK - 1) / BLK;
    pgl_kernel<<<grid, BLK, 0, stream>>>(gains, nbr, out, n);
}

// Round 4
// 305.529 us; speedup vs baseline: 1.0161x; 1.0005x over previous
//
#include <hip/hip_runtime.h>

constexpr int DEG   = 31;   // neighbors per node
constexpr int NEV   = 32;   // events per node (self + neighbors)
constexpr int TH    = 16;   // threshold: track dp[0..15] + absorbing "over"
constexpr int BLK   = 128;  // 15872 B LDS -> 10 blocks/CU

__global__ void zero_out_kernel(float* out) {
    if (threadIdx.x == 0) out[0] = 0.0f;
}

__device__ __forceinline__ float fast_sigmoid(float x) {
    return 1.0f / (1.0f + __expf(-x));
}

__global__ __launch_bounds__(BLK)
void pgl_kernel(const float* __restrict__ gains,
                const int*   __restrict__ nbr,
                float*       __restrict__ out,
                int n) {
    __shared__ int s_idx[BLK * DEG];          // 15872 B
    __shared__ float s_red[BLK / 64];

    const int tid        = threadIdx.x;
    const int blockStart = blockIdx.x * BLK;

    // ---- stage this block's neighbor rows into LDS, coalesced int4 ----
    const int rows  = min(BLK, n - blockStart);
    const int elems = rows * DEG;
    const int base  = blockStart * DEG;

    const int4* nb4 = (const int4*)(nbr + base);
    int4*       s4  = (int4*)s_idx;
    const int nvec  = elems >> 2;
    for (int v = tid; v < nvec; v += BLK) s4[v] = nb4[v];
    for (int e = (nvec << 2) + tid; e < elems; e += BLK) s_idx[e] = nbr[base + e];
    __syncthreads();

    float local = 0.0f;
    const int i = blockStart + tid;
    if (i < n) {
        const int* row = s_idx + tid * DEG;  // stride-31 LDS: 2-way alias only (free)

        // ---- byte offsets for all 32 gathers (self first) ----
        unsigned off[NEV];
        off[0] = (unsigned)i << 2;
        #pragma unroll
        for (int j = 1; j < NEV; ++j) off[j] = ((unsigned)row[j - 1]) << 2;

        // Force ALL offsets resident (LDS reads drained) before the first
        // gather issues, so the 32 loads go out as one uninterrupted clause.
        asm volatile("s_waitcnt lgkmcnt(0)"
                     : "+v"(off[0]),  "+v"(off[1]),  "+v"(off[2]),  "+v"(off[3]),
                       "+v"(off[4]),  "+v"(off[5]),  "+v"(off[6]),  "+v"(off[7]),
                       "+v"(off[8]),  "+v"(off[9]),  "+v"(off[10]), "+v"(off[11]),
                       "+v"(off[12]), "+v"(off[13]), "+v"(off[14]), "+v"(off[15]),
                       "+v"(off[16]), "+v"(off[17]), "+v"(off[18]), "+v"(off[19]),
                       "+v"(off[20]), "+v"(off[21]), "+v"(off[22]), "+v"(off[23]),
                       "+v"(off[24]), "+v"(off[25]), "+v"(off[26]), "+v"(off[27]),
                       "+v"(off[28]), "+v"(off[29]), "+v"(off[30]), "+v"(off[31]));

        // ---- asm-forced gather batch, sc0 = L1-bypass, allocate in L2 ----
        // (4 MB table can never be L1-resident; skipping TCP allocation
        //  avoids tag/MSHR thrash on guaranteed misses.)
        float g[NEV];
        #pragma unroll
        for (int j = 0; j < NEV; ++j)
            asm volatile("global_load_dword %0, %1, %2 sc0"
                         : "=v"(g[j])
                         : "v"(off[j]), "s"(gains));

        float dp[TH];
        dp[0] = 1.0f;
        #pragma unroll
        for (int k = 1; k < TH; ++k) dp[k] = 0.0f;
        float over = 0.0f;

        // ---- wait for oldest 16 loads; tie g[0..15] so uses can't move up ----
        asm volatile("s_waitcnt vmcnt(16)"
                     : "+v"(g[0]), "+v"(g[1]), "+v"(g[2]),  "+v"(g[3]),
                       "+v"(g[4]), "+v"(g[5]), "+v"(g[6]),  "+v"(g[7]),
                       "+v"(g[8]), "+v"(g[9]), "+v"(g[10]), "+v"(g[11]),
                       "+v"(g[12]), "+v"(g[13]), "+v"(g[14]), "+v"(g[15]));

        float p0 = fast_sigmoid(g[0]);
        #pragma unroll
        for (int j = 0; j < 16; ++j) {
            const float pj = (j == 0) ? p0 : fast_sigmoid(g[j]);
            if (j >= TH - 1) over = fmaf(dp[TH - 1], pj, over);
            const int kmax = (j + 1 < TH - 1) ? (j + 1) : (TH - 1);
            #pragma unroll
            for (int k = kmax; k >= 1; --k)
                dp[k] = fmaf(pj, dp[k - 1] - dp[k], dp[k]);
            dp[0] = fmaf(-pj, dp[0], dp[0]);
        }

        // ---- drain the rest; tie g[16..31] ----
        asm volatile("s_waitcnt vmcnt(0)"
                     : "+v"(g[16]), "+v"(g[17]), "+v"(g[18]), "+v"(g[19]),
                       "+v"(g[20]), "+v"(g[21]), "+v"(g[22]), "+v"(g[23]),
                       "+v"(g[24]), "+v"(g[25]), "+v"(g[26]), "+v"(g[27]),
                       "+v"(g[28]), "+v"(g[29]), "+v"(g[30]), "+v"(g[31]));

        #pragma unroll
        for (int j = 16; j < NEV; ++j) {
            const float pj = fast_sigmoid(g[j]);
            over = fmaf(dp[TH - 1], pj, over);
            #pragma unroll
            for (int k = TH - 1; k >= 1; --k)
                dp[k] = fmaf(pj, dp[k - 1] - dp[k], dp[k]);
            dp[0] = fmaf(-pj, dp[0], dp[0]);
        }

        // contribution to -(loss): 0.25*p0 - P(count>=16)
        local = fmaf(0.25f, p0, -over);
    }

    // ---- block reduction: wave shuffle -> LDS -> one atomic per block ----
    #pragma unroll
    for (int off2 = 32; off2 > 0; off2 >>= 1)
        local += __shfl_down(local, off2, 64);
    if ((tid & 63) == 0) s_red[tid >> 6] = local;
    __syncthreads();
    if (tid == 0) {
        float s = 0.0f;
        #pragma unroll
        for (int w = 0; w < BLK / 64; ++w) s += s_red[w];
        atomicAdd(out, s);
    }
}

extern "C" void kernel_launch(void* const* d_in, const int* in_sizes, int n_in,
                              void* d_out, int out_size, void* d_ws, size_t ws_size,
                              hipStream_t stream) {
    const float* gains = (const float*)d_in[0];
    const int*   nbr   = (const int*)d_in[1];
    float*       out   = (float*)d_out;
    const int n = in_sizes[0];

    zero_out_kernel<<<1, 64, 0, stream>>>(out);
    const int grid = (n + BLK - 1) / BLK;
    pgl_kernel<<<grid, BLK, 0, stream>>>(gains, nbr, out, n);
}